// Round 4
// baseline (379.481 us; speedup 1.0000x reference)
//
#include <hip/hip_runtime.h>
#include <math.h>
#include <stdint.h>

// image_batch (32,1,512,512) f32, angles (8,) f32 -> out (32,8,512,512) f32
#define N_IMG 32
#define N_ANG 8
#define H_ 512
#define W_ 512

// Output tile 64x64 (square minimizes rotated-footprint/tile ratio: 3.2x at
// 64x32 -> ~1.9x avg). Source bbox sized PER ANGLE at runtime:
// rows <= 93, pitch LP <= 100 (LP mult-of-4, LP%8==4 for bank spread).
// Worst LDS = 93*100*4 = 37.2 KB, single-buffered (R1: pipelining ~null)
// -> 4 blocks/CU. Staged bytes drop from fixed 25.6 KB/img (3.2x output)
// to angle-dependent ~24-37 KB per 16 KB output (~1.9x avg).
#define TX 64
#define TY 64
#define MAXCH 37
#define LDSW (MAXCH * 256)   // 9472 words = 37.9 KB
// modeB transpose out-stage pitch: 64 rows x 68 words = 4352 words, reuses
// the consumed gather buffer. 68%32=4 -> conflict-free-ish b128.
#define OP 68

// native clang vector type: __builtin_nontemporal_store requires it
// (HIP's float4 is a class and is rejected).
typedef float f32x4 __attribute__((ext_vector_type(4)));

__global__ __launch_bounds__(256, 4) void rotate_tile_kernel(
    const float* __restrict__ img,     // [N_IMG][H][W]
    const float* __restrict__ angles,  // [N_ANG] degrees
    float* __restrict__ out)           // [N_IMG][N_ANG][H][W]
{
    __shared__ float tile[LDSW];

    // ---- XCD-pairing swizzle. Assumption (perf-only): consecutive
    // blockIdx.x round-robin across the 8 XCDs. Put the two angle-streams
    // that read the SAME image half on one XCD (2 x 64 tiles = 128 blocks
    // = one XCD's capacity at 4 blocks/CU) so the 1-MB source image stays
    // L2-resident and staged reads are L2 hits, not fabric traffic.
    const int b    = blockIdx.x;
    const int xcd  = b & 7;
    const int slot = b >> 3;                 // 0..127
    const int sel  = slot & 1;
    const int tnum = slot >> 1;              // tile id 0..63
    const int h    = xcd >> 2;               // image half 0/1
    const int k    = (xcd & 3) + sel * 4;    // angle 0..7
    const int n0   = h * (N_IMG / 2);
    const int tx0  = (tnum & 7) * TX;
    const int ty0  = (tnum >> 3) * TY;

    const int tid  = threadIdx.x;
    const int wid  = tid >> 6;
    const int lane = tid & 63;

    const float rad = angles[k] * 0.017453292519943295f;
    float sa, ca;
    sincosf(rad, &sa, &ca);
    const float cx = (W_ - 1) * 0.5f;
    const float cy = (H_ - 1) * 0.5f;

    // ---- source bbox (block-uniform) from the 4 tile corners ----
    float minsx = 1e30f, maxsx = -1e30f, minsy = 1e30f, maxsy = -1e30f;
#pragma unroll
    for (int cyi = 0; cyi < 2; ++cyi) {
#pragma unroll
        for (int cxi = 0; cxi < 2; ++cxi) {
            const float xr = (float)(tx0 + cxi * (TX - 1)) - cx;
            const float yr = (float)(ty0 + cyi * (TY - 1)) - cy;
            const float sx = ca * xr - sa * yr + cx;
            const float sy = sa * xr + ca * yr + cy;
            minsx = fminf(minsx, sx); maxsx = fmaxf(maxsx, sx);
            minsy = fminf(minsy, sy); maxsy = fmaxf(maxsy, sy);
        }
    }
    const int bx0 = min(max((int)floorf(minsx) - 1, 0), W_ - 1);
    const int by0 = min(max((int)floorf(minsy) - 1, 0), H_ - 1);
    // Margined origins. The left -4 / top -1 pads are only needed when a
    // valid tap can have x0==-1 / y0==-1, i.e. when minsx/minsy < 0 — exact
    // addressing then needs one garbage 4-col group / row staged above-left.
    // Interior tiles skip the pad (keeps LP<=100, rows<=93 -> 37 KB worst).
    const int bx0m = (minsx < 0.0f) ? -4 : (bx0 & ~3);   // mult of 4
    const int by0m = (minsy < 0.0f) ? -1 : by0;
    // staged extents (block-uniform, runtime): cols covers x1max+1 slots,
    // rows covers y1max+1.
    int cols  = (int)floorf(maxsx) + 2 - bx0m;
    int LP    = (cols + 3) & ~3;
    if ((LP & 7) == 0) LP += 4;      // row stride ≡ 4 (mod 8): bank spread
    int rowsS = (int)floorf(maxsy) + 2 - by0m;
    // analysis bounds: LP<=100, rowsS<=93, product<=9300<=LDSW. Safety clamps
    // (no-ops per analysis, guard LDS only):
    LP    = min(LP, 100);
    rowsS = min(rowsS, 94);
    const int nchunk = min((rowsS * LP + 255) >> 8, MAXCH);

    // ---- per-lane staging source offsets: computed ONCE, reused 16 images.
    // Flat LDS word f -> (row,col) with runtime pitch LP (col stays mult-of-4
    // since LP is, so a lane's 16B never crosses an LDS row). Global side
    // clamped in-bounds; clamped (garbage) words only feed weight-0 taps.
    int goff[10];
    int nst = 0;
    for (int s = wid; s < nchunk; s += 4) {
        const int f = s * 256 + lane * 4;
        const int row = (int)((unsigned)f / (unsigned)LP);
        const int col = f - row * LP;
        const int grow = min(max(by0m + row, 0), H_ - 1);
        const int gcol = min(max(bx0m + col, 0), W_ - 4);
        goff[nst++] = grow * W_ + gcol;
    }

    // ---- lane -> output-pixel mapping, chosen per angle to spread LDS banks
    // on the gather: lanes along x when |cos|>=|sin|, along y otherwise.
    // Block-uniform -> no divergence. modeB global stores go through an LDS
    // transpose so the HBM write pattern is always 256-B contiguous runs.
    const bool modeA = fabsf(ca) >= fabsf(sa);
    const int pxg = modeA ? (tid & 15) : (tid >> 4);
    const int py0 = modeA ? (tid >> 4) : (tid & 15);
    const int px  = pxg * 4;

    // ---- per-pixel (16 px/thread = 4 row-blocks x 4 cols) base LDS offset,
    // bilinear fracs, and packed 4-bit tap-validity masks (image-independent).
    // Masks zero the TAP VALUE (reference semantics: weight kept, value 0).
    int      obw[4][4];
    float    wxv[4][4], wyv[4][4];
    unsigned vm[2] = {0u, 0u};       // 4 bits/px, 8 px/reg
#pragma unroll
    for (int p = 0; p < 4; ++p) {
        const int   yy = ty0 + py0 + p * 16;
        const float yr = (float)yy - cy;
#pragma unroll
        for (int j = 0; j < 4; ++j) {
            const int   xx = tx0 + px + j;
            const float xr = (float)xx - cx;
            const float sxs = ca * xr - sa * yr + cx;
            const float sys = sa * xr + ca * yr + cy;
            const float x0f = floorf(sxs), y0f = floorf(sys);
            wxv[p][j] = sxs - x0f;
            wyv[p][j] = sys - y0f;
            const int x0 = (int)x0f, y0 = (int)y0f;
            const unsigned vx0 = ((unsigned)x0       < (unsigned)W_) ? 1u : 0u;
            const unsigned vx1 = ((unsigned)(x0 + 1) < (unsigned)W_) ? 1u : 0u;
            const unsigned vy0 = ((unsigned)y0       < (unsigned)H_) ? 1u : 0u;
            const unsigned vy1 = ((unsigned)(y0 + 1) < (unsigned)H_) ? 1u : 0u;
            // valid taps are never clamped (margins guarantee range);
            // clamping only keeps weight-0 taps inside the staged array.
            const int lx = min(max(x0 - bx0m, 0), LP - 2);
            const int ly = min(max(y0 - by0m, 0), rowsS - 2);
            obw[p][j] = ly * LP + lx;
            const unsigned bits = (vy0 & vx0) | ((vy0 & vx1) << 1)
                                | ((vy1 & vx0) << 2) | ((vy1 & vx1) << 3);
            vm[p >> 1] |= bits << ((((p & 1) << 2) + j) << 2);
        }
    }

    // ---- per-image: stage bbox -> LDS, gather, store (single buffer;
    // R1 proved pipelining ~null -> keep barriers simple, 4 blocks/CU TLP).
    for (int idx = 0; idx < N_IMG / 2; ++idx) {
        const int n = n0 + idx;
        const float* __restrict__ ib = img + (size_t)n * (H_ * W_);
        for (int i = 0; i < nst; ++i) {
            __builtin_amdgcn_global_load_lds(
                (const __attribute__((address_space(1))) void*)(ib + goff[i]),
                (__attribute__((address_space(3))) void*)(&tile[(wid + i * 4) * 256]),
                16, 0, 0);
        }
        asm volatile("s_waitcnt vmcnt(0)" ::: "memory");
        __builtin_amdgcn_s_barrier();

        float* __restrict__ outn =
            out + ((size_t)(n * N_ANG + k) * H_ + ty0) * W_ + tx0;

        if (modeA) {
#pragma unroll
            for (int p = 0; p < 4; ++p) {
                float v[4];
#pragma unroll
                for (int j = 0; j < 4; ++j) {
                    const float* __restrict__ b0 = &tile[obw[p][j]];
                    float t00 = b0[0], t01 = b0[1];
                    float t10 = b0[LP], t11 = b0[LP + 1];
                    const unsigned mb = vm[p >> 1] >> ((((p & 1) << 2) + j) << 2);
                    t00 = (mb & 1u) ? t00 : 0.0f;
                    t01 = (mb & 2u) ? t01 : 0.0f;
                    t10 = (mb & 4u) ? t10 : 0.0f;
                    t11 = (mb & 8u) ? t11 : 0.0f;
                    const float wx = wxv[p][j], wy = wyv[p][j];
                    const float omwx = 1.0f - wx, omwy = 1.0f - wy;
                    v[j] = (omwy * omwx) * t00 + (omwy * wx) * t01
                         + (wy * omwx) * t10 + (wy * wx) * t11;
                }
                f32x4 vv = { v[0], v[1], v[2], v[3] };
                __builtin_nontemporal_store(
                    vv, (f32x4*)(outn + (py0 + p * 16) * W_ + px));
            }
        } else {
            // modeB: gather everything first (all ds_reads retire before the
            // transpose clobbers the staged tile), then LDS transpose, then
            // coalesced nt stores.
            float v[4][4];
#pragma unroll
            for (int p = 0; p < 4; ++p) {
#pragma unroll
                for (int j = 0; j < 4; ++j) {
                    const float* __restrict__ b0 = &tile[obw[p][j]];
                    float t00 = b0[0], t01 = b0[1];
                    float t10 = b0[LP], t11 = b0[LP + 1];
                    const unsigned mb = vm[p >> 1] >> ((((p & 1) << 2) + j) << 2);
                    t00 = (mb & 1u) ? t00 : 0.0f;
                    t01 = (mb & 2u) ? t01 : 0.0f;
                    t10 = (mb & 4u) ? t10 : 0.0f;
                    t11 = (mb & 8u) ? t11 : 0.0f;
                    const float wx = wxv[p][j], wy = wyv[p][j];
                    const float omwx = 1.0f - wx, omwy = 1.0f - wy;
                    v[p][j] = (omwy * omwx) * t00 + (omwy * wx) * t01
                            + (wy * omwx) * t10 + (wy * wx) * t11;
                }
            }
            asm volatile("s_waitcnt lgkmcnt(0)" ::: "memory");
            __builtin_amdgcn_sched_barrier(0);
            __builtin_amdgcn_s_barrier();
            float* __restrict__ os = tile;
#pragma unroll
            for (int p = 0; p < 4; ++p) {
                f32x4 vv = { v[p][0], v[p][1], v[p][2], v[p][3] };
                *(f32x4*)(os + (py0 + p * 16) * OP + px) = vv;
            }
            asm volatile("s_waitcnt lgkmcnt(0)" ::: "memory");
            __builtin_amdgcn_sched_barrier(0);
            __builtin_amdgcn_s_barrier();
            const int rx = (tid & 15) * 4;
            const int ry = tid >> 4;
#pragma unroll
            for (int p = 0; p < 4; ++p) {
                f32x4 t = *(f32x4*)(os + (ry + p * 16) * OP + rx);
                __builtin_nontemporal_store(
                    t, (f32x4*)(outn + (ry + p * 16) * W_ + rx));
            }
        }

        // end-of-image: every wave drains its own LDS ops before signaling,
        // so the next image's staging can't clobber in-flight reads. Global
        // stores stay in flight (no vmcnt drain needed for LDS safety).
        asm volatile("s_waitcnt lgkmcnt(0)" ::: "memory");
        __builtin_amdgcn_sched_barrier(0);
        __builtin_amdgcn_s_barrier();
    }
}

extern "C" void kernel_launch(void* const* d_in, const int* in_sizes, int n_in,
                              void* d_out, int out_size, void* d_ws, size_t ws_size,
                              hipStream_t stream) {
    const float* img    = (const float*)d_in[0];
    const float* angles = (const float*)d_in[1];
    float* out          = (float*)d_out;

    dim3 block(256, 1, 1);
    dim3 grid(1024, 1, 1);   // 8 angles x 2 halves x 64 tiles, XCD-swizzled
    rotate_tile_kernel<<<grid, block, 0, stream>>>(img, angles, out);
}

// Round 5
// 332.038 us; speedup vs baseline: 1.1429x; 1.1429x over previous
//
#include <hip/hip_runtime.h>
#include <math.h>
#include <stdint.h>

// image_batch (32,1,512,512) f32, angles (8,) f32 -> out (32,8,512,512) f32
#define N_IMG 32
#define N_ANG 8
#define H_ 512
#define W_ 512

// Output tile 64x32 (R2 structure — best measured 339 us). Rotated source
// footprint <= ~72 px/axis; staged bbox is rows(angle-dependent, <=76) x
// pitch 84 words (compile-time: keeps ds_read2 offset folding; 84%32=20
// bank spread). Max 25 chunks of 256 words = 25.6 KB/buffer, DOUBLE-BUFFERED
// (51.2 KB) -> 3 blocks/CU; staging of image n+1 overlaps compute of image n.
// NEW vs R2: (1) nontemporal output stores — the 268-MB write stream no
// longer evicts the 1-MB source image from the per-XCD L2, so the 26x
// re-read of each image is served from L2, not Infinity Cache;
// (2) row-adaptive staging: near-axis angles stage ~half the rows.
#define TX 64
#define TY 32
#define LP 84
#define MAXCH 25
#define LWORDS (MAXCH * 256)
// modeB transpose out-stage pitch: 32 rows x 68 words, reuses the consumed
// gather buffer. 68%32=4 -> conflict-free-ish b128.
#define OP 68

// native clang vector type: __builtin_nontemporal_store requires it
// (HIP float4 is a class and is rejected).
typedef float f32x4 __attribute__((ext_vector_type(4)));

__global__ __launch_bounds__(256, 3) void rotate_tile_kernel(
    const float* __restrict__ img,     // [N_IMG][H][W]
    const float* __restrict__ angles,  // [N_ANG] degrees
    float* __restrict__ out)           // [N_IMG][N_ANG][H][W]
{
    __shared__ float tile[2 * LWORDS];

    const int bz   = blockIdx.z;
    const int k    = bz >> 1;                  // angle
    const int n0   = (bz & 1) * (N_IMG / 2);   // image half
    const int tx0  = blockIdx.x * TX;
    const int ty0  = blockIdx.y * TY;
    const int tid  = threadIdx.x;
    const int wid  = tid >> 6;
    const int lane = tid & 63;

    const float rad = angles[k] * 0.017453292519943295f;
    float sa, ca;
    sincosf(rad, &sa, &ca);
    const float cx = (W_ - 1) * 0.5f;
    const float cy = (H_ - 1) * 0.5f;

    // ---- source bbox (block-uniform) from the 4 tile corners ----
    float minsx = 1e30f, maxsx = -1e30f, minsy = 1e30f, maxsy = -1e30f;
#pragma unroll
    for (int cyi = 0; cyi < 2; ++cyi) {
#pragma unroll
        for (int cxi = 0; cxi < 2; ++cxi) {
            const float xr = (float)(tx0 + cxi * (TX - 1)) - cx;
            const float yr = (float)(ty0 + cyi * (TY - 1)) - cy;
            const float sx = ca * xr - sa * yr + cx;
            const float sy = sa * xr + ca * yr + cy;
            minsx = fminf(minsx, sx); maxsx = fmaxf(maxsx, sx);
            minsy = fminf(minsy, sy); maxsy = fmaxf(maxsy, sy);
        }
    }
    const int bx0 = min(max((int)floorf(minsx) - 1, 0), W_ - 1);
    const int by0 = min(max((int)floorf(minsy) - 1, 0), H_ - 1);
    // margined origins: one extra staged row and 4-col group at top/left so
    // taps x1=x0+1 / y1=y0+1 are always base+1 / base+LP (derived offsets
    // stay exact at the image boundary).
    const int bx0m = (bx0 & ~3) - 4;   // multiple of 4 (possibly negative)
    const int by0m = by0 - 1;
    // row-adaptive staged extent: covers y1max = floor(maxsy)+1.
    // rowsS <= (64*|s|+32*|c| + margins) <= 76; 76*84 = 6384 <= 6400 words.
    const int rowsS  = min((int)floorf(maxsy) + 2 - by0m, 76);
    const int nchunk = min((rowsS * LP + 255) >> 8, MAXCH);

    // ---- per-lane staging source offsets: computed ONCE, reused 16 images.
    // Flat LDS word f -> (row,col) with pitch 84 (col stays mult-of-4, so a
    // lane's 16B never crosses an LDS row). Global side clamped in-bounds;
    // clamped (garbage) words are only ever gathered with weight 0.
    int goff[7];
    int nst = 0;
    for (int s = wid; s < nchunk; s += 4) {
        const int f   = s * 256 + lane * 4;
        const int row = f / LP;
        const int col = f - row * LP;
        const int grow = min(max(by0m + row, 0), H_ - 1);
        const int gcol = min(max(bx0m + col, 0), W_ - 4);
        goff[nst++] = grow * W_ + gcol;
    }

    // ---- lane -> output-pixel mapping, chosen per angle to spread LDS banks
    // on the gather: lanes along x when |cos|>=|sin|, along y otherwise.
    // Block-uniform -> no divergence. modeB global stores go through an LDS
    // transpose so the HBM write pattern is always 256-B contiguous runs.
    const bool modeA = fabsf(ca) >= fabsf(sa);
    const int pxg = modeA ? (tid & 15) : (tid >> 4);
    const int py0 = modeA ? (tid >> 4) : (tid & 15);
    const int px  = pxg * 4;

    // ---- per-pixel base LDS offset + 4 premultiplied bilinear weights
    // (image-independent; validity folded into the weights).
    int   ob[2][4];
    float w00[2][4], w01[2][4], w10[2][4], w11[2][4];
#pragma unroll
    for (int p = 0; p < 2; ++p) {
        const int   yy = ty0 + py0 + p * 16;
        const float yr = (float)yy - cy;
#pragma unroll
        for (int j = 0; j < 4; ++j) {
            const int   xx = tx0 + px + j;
            const float xr = (float)xx - cx;
            const float sxs = ca * xr - sa * yr + cx;
            const float sys = sa * xr + ca * yr + cy;
            const float x0f = floorf(sxs), y0f = floorf(sys);
            const float wx = sxs - x0f, wy = sys - y0f;
            const int x0 = (int)x0f, y0 = (int)y0f;
            const bool vx0 = ((unsigned)x0       < (unsigned)W_);
            const bool vx1 = ((unsigned)(x0 + 1) < (unsigned)W_);
            const bool vy0 = ((unsigned)y0       < (unsigned)H_);
            const bool vy1 = ((unsigned)(y0 + 1) < (unsigned)H_);
            // valid taps are never clamped (margins guarantee range);
            // clamping only keeps weight-0 taps inside the staged region.
            const int lx = min(max(x0 - bx0m, 0), 82);
            const int ly = min(max(y0 - by0m, 0), rowsS - 2);
            ob[p][j] = ly * LP + lx;
            const float omwx = 1.0f - wx, omwy = 1.0f - wy;
            w00[p][j] = omwy * omwx * (float)(vy0 && vx0);
            w01[p][j] = omwy * wx   * (float)(vy0 && vx1);
            w10[p][j] = wy   * omwx * (float)(vy1 && vx0);
            w11[p][j] = wy   * wx   * (float)(vy1 && vx1);
        }
    }

    // ---- staging helper: issue this wave's chunks of image n into buffer b.
    auto stage_img = [&](int n, int b) {
        const float* __restrict__ ib = img + (size_t)n * (H_ * W_);
        float* dst0 = &tile[b * LWORDS];
        for (int i = 0; i < nst; ++i) {
            __builtin_amdgcn_global_load_lds(
                (const __attribute__((address_space(1))) void*)(ib + goff[i]),
                (__attribute__((address_space(3))) void*)(dst0 + (wid + i * 4) * 256),
                16, 0, 0);
        }
    };

    // ---- 2-phase pipeline over the 16 images (T3 minimum recipe):
    //   prologue: stage img0 -> buf0; vmcnt(0); barrier
    //   iter n:   issue stage img n+1 -> buf^1   (overlaps with...)
    //             compute img n from buf; store (modeB: via LDS transpose)
    //             vmcnt(2); barrier              (drain prefetch loads only —
    //                                             the 2 newest VMEM ops are
    //                                             this image's stores, left
    //                                             in flight)
    stage_img(n0, 0);
    asm volatile("s_waitcnt vmcnt(0)" ::: "memory");
    __builtin_amdgcn_s_barrier();

    int cur = 0;
    for (int idx = 0; idx < N_IMG / 2; ++idx) {
        const int n = n0 + idx;
        const bool more = (idx + 1 < N_IMG / 2);
        if (more) {
            stage_img(n + 1, cur ^ 1);
            // pin issue order: [prefetch loads][compute -> stores] so the
            // counted vmcnt(2) below always drains exactly the loads.
            __builtin_amdgcn_sched_barrier(0);
        }

        const float* __restrict__ tb = &tile[cur * LWORDS];
        float* __restrict__ outn =
            out + ((size_t)(n * N_ANG + k) * H_ + ty0) * W_ + tx0;

        // gather ALL taps first (both p) so modeB can repurpose tb afterward
        float v[2][4];
#pragma unroll
        for (int p = 0; p < 2; ++p) {
#pragma unroll
            for (int j = 0; j < 4; ++j) {
                const float* __restrict__ b0 = &tb[ob[p][j]];
                // taps: (y0,x0)=b0[0], (y0,x1)=b0[1], (y1,x0)=b0[LP], (y1,x1)=b0[LP+1]
                v[p][j] = w00[p][j] * b0[0]
                        + w01[p][j] * b0[1]
                        + w10[p][j] * b0[LP]
                        + w11[p][j] * b0[LP + 1];
            }
        }

        if (modeA) {
            // lanes already span x: 16 lanes x 16B = 256-B contiguous runs.
#pragma unroll
            for (int p = 0; p < 2; ++p) {
                f32x4 vv = { v[p][0], v[p][1], v[p][2], v[p][3] };
                __builtin_nontemporal_store(
                    vv, (f32x4*)(outn + (py0 + p * 16) * W_ + px));
            }
        } else {
            // modeB: lanes span y -> direct stores would be 16-B scatters at
            // 2-KB stride. Transpose through the just-consumed gather buffer,
            // then store coalesced.
            // barrier: every wave's v[] is in registers => all ds_reads of tb
            // retired => tb is safe to clobber. Raw s_barrier (no vmcnt drain
            // -- prefetch stays in flight).
            __builtin_amdgcn_s_barrier();
            float* __restrict__ os = (float*)&tile[cur * LWORDS];
#pragma unroll
            for (int p = 0; p < 2; ++p) {
                f32x4 vv = { v[p][0], v[p][1], v[p][2], v[p][3] };
                *(f32x4*)(os + (py0 + p * 16) * OP + px) = vv;
            }
            // drain own ds_writes (lgkm only!), then barrier: transposed tile
            // visible to all waves. sched_barrier pins the ds_reads below
            // after the wait (rule #18).
            asm volatile("s_waitcnt lgkmcnt(0)" ::: "memory");
            __builtin_amdgcn_sched_barrier(0);
            __builtin_amdgcn_s_barrier();
            const int rx = (tid & 15) * 4;   // coalesced mapping (modeA-style)
            const int ry = tid >> 4;
#pragma unroll
            for (int p = 0; p < 2; ++p) {
                f32x4 t = *(f32x4*)(os + (ry + p * 16) * OP + rx);
                __builtin_nontemporal_store(
                    t, (f32x4*)(outn + (ry + p * 16) * W_ + rx));
            }
        }

        if (more) {
            // Drain the prefetch loads (oldest in flight); leave this image's
            // 2 output stores (newest) in flight — their ack latency stays
            // off the critical path.
            asm volatile("s_waitcnt vmcnt(2)" ::: "memory");
            __builtin_amdgcn_s_barrier();
            cur ^= 1;
        }
    }
}

extern "C" void kernel_launch(void* const* d_in, const int* in_sizes, int n_in,
                              void* d_out, int out_size, void* d_ws, size_t ws_size,
                              hipStream_t stream) {
    const float* img    = (const float*)d_in[0];
    const float* angles = (const float*)d_in[1];
    float* out          = (float*)d_out;

    dim3 block(256, 1, 1);
    dim3 grid(W_ / TX, H_ / TY, N_ANG * 2);  // 8 x 16 x 16 = 2048 blocks
    rotate_tile_kernel<<<grid, block, 0, stream>>>(img, angles, out);
}